// Round 1
// baseline (379.163 us; speedup 1.0000x reference)
//
#include <hip/hip_runtime.h>

// StyleAttentionExtractor: B=16, C=512, H=W=64 (HW=4096), S=19, seg 256x256.
// out[b,s,:] = where(cnt>0, relu(maskedmean(x)) @ Ws[s]^T + bs[s], 0)

#define NB 16
#define NS 19
#define NC 512
#define NHW 4096

// ---------------- K1: build 19-bit mask word per (b,hw) + count partials ----
// nearest resize 256->64: src index = 4*dst index (floor(i*256/64) = 4i).
__global__ __launch_bounds__(256) void k1_mask(const float* __restrict__ seg,
                                               unsigned int* __restrict__ bm,
                                               unsigned int* __restrict__ cnt_part) {
  int t = threadIdx.x;
  int bid = blockIdx.x;          // 256 = 16 b * 16 chunks of 256 hw
  int b = bid >> 4;
  int chunk = bid & 15;
  int hw = (chunk << 8) + t;
  int h = hw >> 6, w = hw & 63;
  const float* p = seg + (size_t)b * NS * 65536 + (size_t)(h << 2) * 256 + (w << 2);
  unsigned int bits = 0u;
#pragma unroll
  for (int s = 0; s < NS; ++s) {
    float v = p[(size_t)s * 65536];
    if (v != 0.0f) bits |= (1u << s);
  }
  bm[(b << 12) + hw] = bits;
  // per-wave count partials (64 hw each), no atomics needed
  int wave = t >> 6, lane = t & 63;
#pragma unroll
  for (int s = 0; s < NS; ++s) {
    unsigned long long bal = __ballot((bits >> s) & 1u);
    if (lane == 0)
      cnt_part[(size_t)((b << 6) + (chunk << 2) + wave) * NS + s] =
          (unsigned int)__popcll(bal);
  }
}

// ---------------- K2: masked segment sums, streaming pass over x ------------
// Wave owns (b, 4 channels, half of hw). Lanes cover hw via float4 loads.
// acc[4][19] in registers; butterfly reduce across 64 lanes at the end.
__global__ __launch_bounds__(256) void k2_sums(const float* __restrict__ x,
                                               const unsigned int* __restrict__ bm,
                                               float* __restrict__ sums) {
  int bid = blockIdx.x;            // 1024 = b(16) * cgidx(32) * half(2)
  int b = bid >> 6;
  int cgidx = (bid >> 1) & 31;
  int half = bid & 1;
  int wave = threadIdx.x >> 6, lane = threadIdx.x & 63;
  int cg = (cgidx << 2) + wave;    // 0..127 channel-group of 4
  int c0 = cg << 2;
  const float4* px0 = (const float4*)(x + ((size_t)(b * NC + c0 + 0) << 12));
  const float4* px1 = (const float4*)(x + ((size_t)(b * NC + c0 + 1) << 12));
  const float4* px2 = (const float4*)(x + ((size_t)(b * NC + c0 + 2) << 12));
  const float4* px3 = (const float4*)(x + ((size_t)(b * NC + c0 + 3) << 12));
  const uint4* pbm = (const uint4*)(bm + ((size_t)b << 12));
  int base = (half << 9) + lane;   // index in float4 units

  float acc[4][NS];
#pragma unroll
  for (int ci = 0; ci < 4; ++ci)
#pragma unroll
    for (int s = 0; s < NS; ++s) acc[ci][s] = 0.0f;

#pragma unroll 2
  for (int it = 0; it < 8; ++it) {
    int idx = base + (it << 6);
    float4 xv0 = px0[idx];
    float4 xv1 = px1[idx];
    float4 xv2 = px2[idx];
    float4 xv3 = px3[idx];
    uint4 mm = pbm[idx];           // L2-hot (256 KB total, reused by 128 cgroups)
#pragma unroll
    for (int s = 0; s < NS; ++s) {
      float m0 = (float)((mm.x >> s) & 1u);
      float m1 = (float)((mm.y >> s) & 1u);
      float m2 = (float)((mm.z >> s) & 1u);
      float m3 = (float)((mm.w >> s) & 1u);
      acc[0][s] += xv0.x * m0; acc[0][s] += xv0.y * m1; acc[0][s] += xv0.z * m2; acc[0][s] += xv0.w * m3;
      acc[1][s] += xv1.x * m0; acc[1][s] += xv1.y * m1; acc[1][s] += xv1.z * m2; acc[1][s] += xv1.w * m3;
      acc[2][s] += xv2.x * m0; acc[2][s] += xv2.y * m1; acc[2][s] += xv2.z * m2; acc[2][s] += xv2.w * m3;
      acc[3][s] += xv3.x * m0; acc[3][s] += xv3.y * m1; acc[3][s] += xv3.z * m2; acc[3][s] += xv3.w * m3;
    }
  }

  // cross-lane reduction + store partial sums [half][b][s][c]
  float* sp = sums + (((size_t)half * NB + b) * NS) * (size_t)NC + c0;
#pragma unroll
  for (int ci = 0; ci < 4; ++ci) {
#pragma unroll
    for (int s = 0; s < NS; ++s) {
      float v = acc[ci][s];
#pragma unroll
      for (int off = 32; off > 0; off >>= 1) v += __shfl_xor(v, off, 64);
      if (lane == 0) sp[(size_t)s * NC + ci] = v;
    }
  }
}

// ---------------- K3: mean -> relu -> per-segment linear + bias -------------
// Block per (b,s). feat in LDS; wave per c_out, lanes along c_in (coalesced).
__global__ __launch_bounds__(256) void k3_out(const float* __restrict__ sums,
                                              const unsigned int* __restrict__ cnt_part,
                                              const float* __restrict__ Ws,
                                              const float* __restrict__ bsv,
                                              float* __restrict__ out) {
  __shared__ __align__(16) float feat[NC];
  int bid = blockIdx.x;  // 304 = B*S
  int b = bid / NS, s = bid - b * NS;
  int t = threadIdx.x, lane = t & 63, wave = t >> 6;

  unsigned int cp = cnt_part[(size_t)((b << 6) + lane) * NS + s];
#pragma unroll
  for (int off = 32; off > 0; off >>= 1) cp += __shfl_xor(cp, off, 64);

  float* o = out + ((size_t)(b * NS + s)) * NC;
  if (cp == 0u) {                  // zero-area segment: output stays zero
    float2 z; z.x = 0.0f; z.y = 0.0f;
    ((float2*)o)[t] = z;
    return;
  }
  float inv = 1.0f / (float)cp;
  const float* s0 = sums + ((size_t)(b * NS + s)) * NC;
  const float* s1 = sums + ((size_t)((NB + b) * NS + s)) * NC;
  for (int i = t; i < NC; i += 256) {
    float v = (s0[i] + s1[i]) * inv;
    feat[i] = v > 0.0f ? v : 0.0f;
  }
  __syncthreads();

  const float* Wp = Ws + (size_t)s * NC * NC;
  const float4* fv = (const float4*)feat;
#pragma unroll 2
  for (int co = wave; co < NC; co += 4) {
    const float4* wr = (const float4*)(Wp + (size_t)co * NC);
    float4 w0 = wr[lane];
    float4 w1 = wr[64 + lane];
    float4 f0 = fv[lane];
    float4 f1 = fv[64 + lane];
    float a = w0.x * f0.x + w0.y * f0.y + w0.z * f0.z + w0.w * f0.w +
              w1.x * f1.x + w1.y * f1.y + w1.z * f1.z + w1.w * f1.w;
#pragma unroll
    for (int off = 32; off > 0; off >>= 1) a += __shfl_xor(a, off, 64);
    if (lane == 0) o[co] = a + bsv[(size_t)s * NC + co];
  }
}

extern "C" void kernel_launch(void* const* d_in, const int* in_sizes, int n_in,
                              void* d_out, int out_size, void* d_ws, size_t ws_size,
                              hipStream_t stream) {
  const float* x   = (const float*)d_in[0];   // [16,512,64,64]
  const float* seg = (const float*)d_in[1];   // [16,19,256,256]
  const float* Ws  = (const float*)d_in[2];   // [19,512,512]
  const float* bsv = (const float*)d_in[3];   // [19,512]
  float* out = (float*)d_out;                 // [16,19,512]

  char* ws = (char*)d_ws;
  unsigned int* bm       = (unsigned int*)(ws);                 // 16*4096*4   = 262144 B
  unsigned int* cnt_part = (unsigned int*)(ws + 262144);        // 16*64*19*4  = 77824 B
  float*        sums     = (float*)(ws + 262144 + 77824);       // 2*16*19*512*4 = 1245184 B
  // total ws use: 1,585,152 B

  k1_mask<<<256, 256, 0, stream>>>(seg, bm, cnt_part);
  k2_sums<<<1024, 256, 0, stream>>>(x, bm, sums);
  k3_out<<<NB * NS, 256, 0, stream>>>(sums, cnt_part, Ws, bsv, out);
}

// Round 2
// 298.545 us; speedup vs baseline: 1.2700x; 1.2700x over previous
//
#include <hip/hip_runtime.h>

// StyleAttentionExtractor: B=16, C=512, H=W=64 (HW=4096), S=19, seg 256x256.
// out[b,s,:] = where(cnt>0, relu(maskedmean(x)) @ Ws[s]^T + bs[s], 0)

#define NB 16
#define NS 19
#define NC 512
#define NHW 4096

// ---------------- K1: build 19-bit mask word per (b,hw) + count partials ----
// nearest resize 256->64: src index = 4*dst index (floor(i*256/64) = 4i).
__global__ __launch_bounds__(256) void k1_mask(const float* __restrict__ seg,
                                               unsigned int* __restrict__ bm,
                                               unsigned int* __restrict__ cnt_part) {
  int t = threadIdx.x;
  int bid = blockIdx.x;          // 256 = 16 b * 16 chunks of 256 hw
  int b = bid >> 4;
  int chunk = bid & 15;
  int hw = (chunk << 8) + t;
  int h = hw >> 6, w = hw & 63;
  const float* p = seg + (size_t)b * NS * 65536 + (size_t)(h << 2) * 256 + (w << 2);
  unsigned int bits = 0u;
#pragma unroll
  for (int s = 0; s < NS; ++s) {
    float v = p[(size_t)s * 65536];
    if (v != 0.0f) bits |= (1u << s);
  }
  bm[(b << 12) + hw] = bits;
  // per-wave count partials (64 hw each), no atomics needed
  int wave = t >> 6, lane = t & 63;
#pragma unroll
  for (int s = 0; s < NS; ++s) {
    unsigned long long bal = __ballot((bits >> s) & 1u);
    if (lane == 0)
      cnt_part[(size_t)((b << 6) + (chunk << 2) + wave) * NS + s] =
          (unsigned int)__popcll(bal);
  }
}

// ---------------- K2: masked segment sums, streaming pass over x ------------
// Wave owns (b, 4 channels, half of hw). Lanes cover hw via float4 loads.
// acc[4][19] in registers; butterfly reduce across 64 lanes at the end.
__global__ __launch_bounds__(256) void k2_sums(const float* __restrict__ x,
                                               const unsigned int* __restrict__ bm,
                                               float* __restrict__ sums) {
  int bid = blockIdx.x;            // 1024 = b(16) * cgidx(32) * half(2)
  int b = bid >> 6;
  int cgidx = (bid >> 1) & 31;
  int half = bid & 1;
  int wave = threadIdx.x >> 6, lane = threadIdx.x & 63;
  int cg = (cgidx << 2) + wave;    // 0..127 channel-group of 4
  int c0 = cg << 2;
  const float4* px0 = (const float4*)(x + ((size_t)(b * NC + c0 + 0) << 12));
  const float4* px1 = (const float4*)(x + ((size_t)(b * NC + c0 + 1) << 12));
  const float4* px2 = (const float4*)(x + ((size_t)(b * NC + c0 + 2) << 12));
  const float4* px3 = (const float4*)(x + ((size_t)(b * NC + c0 + 3) << 12));
  const uint4* pbm = (const uint4*)(bm + ((size_t)b << 12));
  int base = (half << 9) + lane;   // index in float4 units

  float acc[4][NS];
#pragma unroll
  for (int ci = 0; ci < 4; ++ci)
#pragma unroll
    for (int s = 0; s < NS; ++s) acc[ci][s] = 0.0f;

#pragma unroll 2
  for (int it = 0; it < 8; ++it) {
    int idx = base + (it << 6);
    float4 xv0 = px0[idx];
    float4 xv1 = px1[idx];
    float4 xv2 = px2[idx];
    float4 xv3 = px3[idx];
    uint4 mm = pbm[idx];           // L2-hot (256 KB total, reused by 128 cgroups)
#pragma unroll
    for (int s = 0; s < NS; ++s) {
      float m0 = (float)((mm.x >> s) & 1u);
      float m1 = (float)((mm.y >> s) & 1u);
      float m2 = (float)((mm.z >> s) & 1u);
      float m3 = (float)((mm.w >> s) & 1u);
      acc[0][s] += xv0.x * m0; acc[0][s] += xv0.y * m1; acc[0][s] += xv0.z * m2; acc[0][s] += xv0.w * m3;
      acc[1][s] += xv1.x * m0; acc[1][s] += xv1.y * m1; acc[1][s] += xv1.z * m2; acc[1][s] += xv1.w * m3;
      acc[2][s] += xv2.x * m0; acc[2][s] += xv2.y * m1; acc[2][s] += xv2.z * m2; acc[2][s] += xv2.w * m3;
      acc[3][s] += xv3.x * m0; acc[3][s] += xv3.y * m1; acc[3][s] += xv3.z * m2; acc[3][s] += xv3.w * m3;
    }
  }

  // cross-lane reduction + store partial sums [half][b][s][c]
  float* sp = sums + (((size_t)half * NB + b) * NS) * (size_t)NC + c0;
#pragma unroll
  for (int ci = 0; ci < 4; ++ci) {
#pragma unroll
    for (int s = 0; s < NS; ++s) {
      float v = acc[ci][s];
#pragma unroll
      for (int off = 32; off > 0; off >>= 1) v += __shfl_xor(v, off, 64);
      if (lane == 0) sp[(size_t)s * NC + ci] = v;
    }
  }
}

// ---------------- K3a: counts -> feat = relu(mean), zero-mask ---------------
// Block per (b,s). Writes feat[s][b][ci] (contiguous per s) + mask[s][b].
__global__ __launch_bounds__(256) void k3a_feat(const float* __restrict__ sums,
                                                const unsigned int* __restrict__ cnt_part,
                                                float* __restrict__ featbuf,
                                                float* __restrict__ maskv) {
  int bid = blockIdx.x;  // 304 = B*S
  int b = bid / NS, s = bid - b * NS;
  int t = threadIdx.x, lane = t & 63;

  unsigned int cp = cnt_part[(size_t)((b << 6) + lane) * NS + s];
#pragma unroll
  for (int off = 32; off > 0; off >>= 1) cp += __shfl_xor(cp, off, 64);

  float* f = featbuf + ((size_t)s * NB + b) * NC;
  if (cp == 0u) {
    ((float2*)f)[t] = make_float2(0.0f, 0.0f);
    if (t == 0) maskv[s * NB + b] = 0.0f;
    return;
  }
  if (t == 0) maskv[s * NB + b] = 1.0f;
  float inv = 1.0f / (float)cp;
  const float* s0 = sums + ((size_t)(b * NS + s)) * NC;
  const float* s1 = sums + ((size_t)((NB + b) * NS + s)) * NC;
#pragma unroll
  for (int k = 0; k < 2; ++k) {
    int i = t + (k << 8);
    float v = (s0[i] + s1[i]) * inv;
    f[i] = v > 0.0f ? v : 0.0f;
  }
}

// ---------------- K3b: per-segment linear, Ws read exactly once -------------
// Grid 19*128 blocks; block stages feat[s] (16x512 = 32 KB) in LDS; each of
// 4 waves owns one c_out row: coalesced 2 KB Ws row, dot vs all 16 batches.
__global__ __launch_bounds__(256) void k3b_lin(const float* __restrict__ featbuf,
                                               const float* __restrict__ maskv,
                                               const float* __restrict__ Ws,
                                               const float* __restrict__ bsv,
                                               float* __restrict__ out) {
  __shared__ __align__(16) float feat[NB * NC];  // 32 KB
  int bid = blockIdx.x;          // 2432 = s(19) * cotile(128)
  int s = bid >> 7;
  int cotile = (bid & 127) << 2;
  int t = threadIdx.x, lane = t & 63, wave = t >> 6;
  int co = cotile + wave;

  // issue Ws row load first (longest latency, read-once from HBM)
  const float4* wr = (const float4*)(Ws + ((size_t)s * NC + co) * NC);
  float4 w0 = wr[lane];
  float4 w1 = wr[64 + lane];
  float bias = bsv[s * NC + co];

  // cooperative stage of feat[s] : 8192 floats = 2048 float4
  const float4* fsrc = (const float4*)(featbuf + (size_t)s * NB * NC);
  float4* fdst = (float4*)feat;
#pragma unroll
  for (int k = 0; k < 8; ++k) fdst[t + (k << 8)] = fsrc[t + (k << 8)];
  __syncthreads();

  const float4* fv = (const float4*)feat;
  float accb[NB];
#pragma unroll
  for (int b = 0; b < NB; ++b) {
    float4 f0 = fv[(b << 7) + lane];
    float4 f1 = fv[(b << 7) + 64 + lane];
    accb[b] = w0.x * f0.x + w0.y * f0.y + w0.z * f0.z + w0.w * f0.w +
              w1.x * f1.x + w1.y * f1.y + w1.z * f1.z + w1.w * f1.w;
  }
#pragma unroll
  for (int b = 0; b < NB; ++b) {
    float a = accb[b];
#pragma unroll
    for (int off = 32; off > 0; off >>= 1) a += __shfl_xor(a, off, 64);
    if (lane == (b & 63))  // spread the 16 stores across lanes (same value idea: lane b holds it)
      ;
    if (lane == 0) {
      float m = maskv[s * NB + b];
      out[((size_t)(b * NS + s)) * NC + co] = (a + bias) * m;
    }
  }
}

extern "C" void kernel_launch(void* const* d_in, const int* in_sizes, int n_in,
                              void* d_out, int out_size, void* d_ws, size_t ws_size,
                              hipStream_t stream) {
  const float* x   = (const float*)d_in[0];   // [16,512,64,64]
  const float* seg = (const float*)d_in[1];   // [16,19,256,256]
  const float* Ws  = (const float*)d_in[2];   // [19,512,512]
  const float* bsv = (const float*)d_in[3];   // [19,512]
  float* out = (float*)d_out;                 // [16,19,512]

  char* ws = (char*)d_ws;
  unsigned int* bm       = (unsigned int*)(ws);                 // 262144 B
  unsigned int* cnt_part = (unsigned int*)(ws + 262144);        // 77824 B
  float*        sums     = (float*)(ws + 262144 + 77824);       // 1245184 B
  float*        featbuf  = (float*)(ws + 262144 + 77824 + 1245184);   // 622592 B
  float*        maskv    = (float*)(ws + 262144 + 77824 + 1245184 + 622592); // 1216 B
  // total ws use: ~2.2 MB

  k1_mask<<<256, 256, 0, stream>>>(seg, bm, cnt_part);
  k2_sums<<<1024, 256, 0, stream>>>(x, bm, sums);
  k3a_feat<<<NB * NS, 256, 0, stream>>>(sums, cnt_part, featbuf, maskv);
  k3b_lin<<<NS * 128, 256, 0, stream>>>(featbuf, maskv, Ws, bsv, out);
}